// Round 10
// baseline (156.748 us; speedup 1.0000x reference)
//
#include <hip/hip_runtime.h>

// SimpleSNN: out[r][j] = sum over 10 steps of spikes from a leaky neuron driven by
// cur[r][j] = dot(x[r,:], W[j,:]).  x:[65536,784] f32, W:[10,784] f32, out f32.
//
// R10: mixed precision with a rigorous flip guard. R3/R6/R9 all ~48.5-49.6us with
// wildly different pipelining -> binding constraint is work volume: 513.8M f64 FMA
// (T-A: f64 may be 8cy/instr -> ~27us VALU floor) and/or 205MB HBM (T-B: harness
// 822MB fills flush L3 between replays -> ~33us). This round cuts the f64 work:
//  - main dot in f32: per (r,j) an fma S-chain; per row one ||x||^2 chain.
//    Octant partials (98-term chains) combined exactly in f64.
//    Rigorous error: |cur^ - cur| <= gamma_98 * ||x|| * ||w_j||, gamma_98=5.85e-6
//    (fma-dot bound + Cauchy-Schwarz); we use E = 1.2e-5*||x||*||w_j|| (2x margin,
//    covers the f32 norm-chain's own rounding).
//  - spike feedback amplifies cur error by sum(0.95^k) <= 8.03. Track
//    minm = min_t |mem_t - 1|; if minm <= 8.03*E some decision could flip ->
//    inline f64 recompute (x row + W row from global; ~1-2% of elements, 1-2
//    lanes/wave in a uniform masked 196-iter loop). Unflagged elements provably
//    match the f64-exact recurrence; flagged path = the f64 math that has passed
//    6 rounds with absmax 0.
//  - staging/ring/geometry copied verbatim from R9 (proven): PADW=17, 8-buf ring,
//    4 tiles/period, s_load W (now f32 W32T: 20 SGPRs/tile).

constexpr int ROWS  = 65536;
constexpr int COLS  = 784;
constexpr int NOUT  = 10;
constexpr int STEPS = 10;

constexpr int BR   = 64;           // rows per block (thread r owns one row)
constexpr int TW   = 16;           // tile width (784 = 49*16)
constexpr int NT   = COLS / TW;    // 49 tiles
constexpr int PADW = 17;           // odd dword stride -> conflict-free b32 reads
constexpr int NH   = 8;            // column octants (= waves per block)
constexpr int CPH  = TW / NH;      // 2 cols per thread per tile
constexpr int TPP  = 4;            // tiles per barrier period
constexpr int NP   = 12;           // full periods (tiles 0..47); tile 48 = tail
constexpr int NBUF = 8;            // LDS tile ring
constexpr int BUF_F = BR * PADW;   // 1088 floats per tile buffer

constexpr int WT_BYTES = NOUT * COLS * 4;   // 31360: W32T[c][j] f32 in ws
// wn f64[10] lives at ws + WT_BYTES (8-aligned: 31360 % 8 == 0)

// --- prep: W32T[c][j] f32 + wn[j] = ||w_j|| (f64) ---
__global__ __launch_bounds__(256)
void w_prep(const float* __restrict__ W, float* __restrict__ W32T,
            double* __restrict__ wn) {
    __shared__ double red[256];
    const int j = blockIdx.x;            // 10 blocks
    const int t = threadIdx.x;
    double nrm = 0.0;
    for (int c = t; c < COLS; c += 256) {
        float w = W[(size_t)j * COLS + c];
        W32T[(size_t)c * NOUT + j] = w;
        nrm = fma((double)w, (double)w, nrm);
    }
    red[t] = nrm;
    __syncthreads();
    for (int s = 128; s > 0; s >>= 1) {
        if (t < s) red[t] += red[t + s];
        __syncthreads();
    }
    if (t == 0) wn[j] = sqrt(red[0]);
}

__global__ __launch_bounds__(512, 8)
void snn_fused(const float* __restrict__ x, const float* __restrict__ W,
               const float* __restrict__ W32T, const double* __restrict__ wn,
               float* __restrict__ out) {
    // union: 8 x-tile buffers (34816B) / comb f32 [8][64][11] (22528B)
    __shared__ __align__(16) char smem[NBUF * BUF_F * 4];
    float* bufs = reinterpret_cast<float*>(smem);
    float* comb = reinterpret_cast<float*>(smem);

    const int tid = threadIdx.x;
    const int r   = tid & 63;                                  // lane = row
    const int hu  = __builtin_amdgcn_readfirstlane(tid >> 6);  // wave = col octant
    const size_t row0 = (size_t)blockIdx.x * BR;
    const float* xblk = x + row0 * COLS;

    // staging (verbatim R9): period P = 4 tiles; 16 lanes cover one row's 256B.
    auto issueP = [&](int P, float4* v) {
        #pragma unroll
        for (int k = 0; k < 2; ++k) {
            int s = tid + 512 * k;
            int row = s >> 4, seg = s & 15;
            int t  = P * TPP + (seg >> 2);
            int tc = (t < NT) ? t : NT - 1;
            v[k] = *reinterpret_cast<const float4*>(
                xblk + (size_t)row * COLS + tc * TW + (seg & 3) * 4);
        }
    };
    auto wldsP = [&](int P, const float4* v) {
        #pragma unroll
        for (int k = 0; k < 2; ++k) {
            int s = tid + 512 * k;
            int row = s >> 4, seg = s & 15;
            int t  = P * TPP + (seg >> 2);
            int tc = (t < NT) ? t : NT - 1;
            float* p = bufs + (tc & (NBUF - 1)) * BUF_F + row * PADW + (seg & 3) * 4;
            p[0] = v[k].x; p[1] = v[k].y; p[2] = v[k].z; p[3] = v[k].w;
        }
    };

    float sacc[NOUT];
    #pragma unroll
    for (int j = 0; j < NOUT; ++j) sacc[j] = 0.0f;
    float nacc = 0.0f;                         // || x_row (this octant) ||^2

    float4 v0[2], v1[2];
    issueP(0, v0); wldsP(0, v0);
    issueP(1, v1);
    __syncthreads();

    for (int p = 0; p < NP; ++p) {
        wldsP(p + 1, v1);
        if (p + 2 <= NP) issueP(p + 2, v0);

        #pragma unroll 1                       // keep W at 20 live f32 (R5 lesson)
        for (int u = 0; u < TPP; ++u) {
            const int tt = p * TPP + u;
            const float* src = bufs + (tt & (NBUF - 1)) * BUF_F + r * PADW + hu * CPH;
            const float* wb  = W32T + (size_t)(tt * TW + hu * CPH) * NOUT;  // s_load
            #pragma unroll
            for (int c = 0; c < CPH; ++c) {
                float xv = src[c];             // ds_read, conflict-free (17)
                nacc = fmaf(xv, xv, nacc);
                #pragma unroll
                for (int j = 0; j < NOUT; ++j)
                    sacc[j] = fmaf(xv, wb[c * NOUT + j], sacc[j]);
            }
        }
        __syncthreads();
        v1[0] = v0[0]; v1[1] = v0[1];
    }

    // tail: tile 48
    {
        const int tt = NT - 1;
        const float* src = bufs + (tt & (NBUF - 1)) * BUF_F + r * PADW + hu * CPH;
        const float* wb  = W32T + (size_t)(tt * TW + hu * CPH) * NOUT;
        #pragma unroll
        for (int c = 0; c < CPH; ++c) {
            float xv = src[c];
            nacc = fmaf(xv, xv, nacc);
            #pragma unroll
            for (int j = 0; j < NOUT; ++j)
                sacc[j] = fmaf(xv, wb[c * NOUT + j], sacc[j]);
        }
    }
    __syncthreads();                           // bufs reads done; comb aliases bufs

    #pragma unroll
    for (int j = 0; j < NOUT; ++j)
        comb[(hu * BR + r) * 11 + j] = sacc[j];
    comb[(hu * BR + r) * 11 + 10] = nacc;
    __syncthreads();

    for (int i = tid; i < BR * NOUT; i += 512) {   // 640 outputs
        const int rr = i / NOUT, j = i - rr * NOUT;
        double cur = 0.0, nr2 = 0.0;
        #pragma unroll
        for (int o = 0; o < NH; ++o) {
            cur += (double)comb[(o * BR + rr) * 11 + j];
            nr2 += (double)comb[(o * BR + rr) * 11 + 10];
        }
        // worst-case |cur^ - cur_exact| * feedback amplification (sum 0.95^k <= 8.03)
        const double Emem = 9.7e-5 * sqrt(nr2) * wn[j];   // 8.03 * 1.2e-5 * ||x||*||wj||

        double mem = 0.0, spk = 0.0, s = 0.0, minm = 1e300;
        #pragma unroll
        for (int st = 0; st < STEPS; ++st) {
            mem = 0.95 * mem + cur - spk;      // reset-by-subtraction, thr=1.0
            double d = mem - 1.0;
            minm = fmin(minm, fabs(d));
            spk = (d > 0.0) ? 1.0 : 0.0;
            s  += spk;
        }

        if (minm <= Emem) {                    // decision could flip: exact f64 redo
            const float* xr = x + (row0 + rr) * COLS;
            const float* wr = W + (size_t)j * COLS;
            double a0 = 0.0, a1 = 0.0, a2 = 0.0, a3 = 0.0;
            for (int c = 0; c < COLS; c += 4) {            // uniform masked loop
                float4 xv = *reinterpret_cast<const float4*>(xr + c);
                float4 wv = *reinterpret_cast<const float4*>(wr + c);
                a0 = fma((double)xv.x, (double)wv.x, a0);
                a1 = fma((double)xv.y, (double)wv.y, a1);
                a2 = fma((double)xv.z, (double)wv.z, a2);
                a3 = fma((double)xv.w, (double)wv.w, a3);
            }
            double ce = (a0 + a1) + (a2 + a3);
            mem = 0.0; spk = 0.0; s = 0.0;
            #pragma unroll
            for (int st = 0; st < STEPS; ++st) {
                mem = 0.95 * mem + ce - spk;
                spk = (mem > 1.0) ? 1.0 : 0.0;
                s  += spk;
            }
        }
        out[row0 * NOUT + i] = (float)s;       // coalesced per block
    }
}

extern "C" void kernel_launch(void* const* d_in, const int* in_sizes, int n_in,
                              void* d_out, int out_size, void* d_ws, size_t ws_size,
                              hipStream_t stream) {
    const float* x = (const float*)d_in[0];
    const float* W = (const float*)d_in[1];
    float*  out  = (float*)d_out;
    float*  W32T = (float*)d_ws;
    double* wnrm = (double*)((char*)d_ws + WT_BYTES);

    hipLaunchKernelGGL(w_prep, dim3(NOUT), dim3(256), 0, stream, W, W32T, wnrm);
    hipLaunchKernelGGL(snn_fused, dim3(ROWS / BR), dim3(512), 0, stream,
                       x, W, W32T, wnrm, out);
}

// Round 11
// 60.360 us; speedup vs baseline: 2.5969x; 2.5969x over previous
//
#include <hip/hip_runtime.h>

// SimpleSNN: out[r][j] = sum over 10 steps of spikes from a leaky neuron driven by
// cur[r][j] = dot(x[r,:], W[j,:]).  x:[65536,784] f32, W:[10,784] f32, out f32.
//
// R11 = R10 (f32 main dot + rigorous flip guard; absmax==0, bound validated) with
// the guard cost fixed. R10's 156us was the guard: ~1.6% flag rate -> 64% of
// epilogue waves ran a SERIAL per-lane 196-iter f64 uncoalesced recompute.
//  - flagged (r,j) go to an LDS queue; each is recomputed by a FULL WAVE:
//    lane L sums c=L,L+64,... in f64 (coalesced), __shfl_xor butterfly reduce,
//    lane 0 reruns the recurrence. ~10 entries/block, ~250cy each.
//    (f64 reduction order differs from the serial chain: err ~1e-13 vs flip
//    window ~3e-12-probability ~1e-11 over 655K elements -- same argument that
//    made 6 different f64 orders all absmax==0.)
//  - BUF_F 1088 -> 1089: ring buffers shift 1 bank apart; staging ds_write drops
//    4-way -> 2-way (free). R10 measured 4.9M SQ_LDS_BANK_CONFLICT from this.
//  - everything else verbatim R10: PADW=17 ring, 4 tiles/period, W32T s_load
//    (20 f32/tile, unroll 1 -- R5 SGPR lesson), f32 S-chain + ||x||^2 chain,
//    octant partials combined in f64, Emem = 8.03*1.2e-5*||x||*||w_j||.

constexpr int ROWS  = 65536;
constexpr int COLS  = 784;
constexpr int NOUT  = 10;
constexpr int STEPS = 10;

constexpr int BR   = 64;           // rows per block (thread r owns one row)
constexpr int TW   = 16;           // tile width (784 = 49*16)
constexpr int NT   = COLS / TW;    // 49 tiles
constexpr int PADW = 17;           // odd dword stride -> conflict-free b32 reads
constexpr int NH   = 8;            // column octants (= waves per block)
constexpr int CPH  = TW / NH;      // 2 cols per thread per tile
constexpr int TPP  = 4;            // tiles per barrier period
constexpr int NP   = 12;           // full periods (tiles 0..47); tile 48 = tail
constexpr int NBUF = 8;            // LDS tile ring
constexpr int BUF_F = BR * PADW + 1;  // 1089: ring buffers 1 bank apart
                                      // (1088%32==0 gave R10's 4-way write conflict)

constexpr int WT_BYTES = NOUT * COLS * 4;   // 31360: W32T[c][j] f32 in ws

// --- prep: W32T[c][j] f32 + wn[j] = ||w_j|| (f64) ---
__global__ __launch_bounds__(256)
void w_prep(const float* __restrict__ W, float* __restrict__ W32T,
            double* __restrict__ wn) {
    __shared__ double red[256];
    const int j = blockIdx.x;            // 10 blocks
    const int t = threadIdx.x;
    double nrm = 0.0;
    for (int c = t; c < COLS; c += 256) {
        float w = W[(size_t)j * COLS + c];
        W32T[(size_t)c * NOUT + j] = w;
        nrm = fma((double)w, (double)w, nrm);
    }
    red[t] = nrm;
    __syncthreads();
    for (int s = 128; s > 0; s >>= 1) {
        if (t < s) red[t] += red[t + s];
        __syncthreads();
    }
    if (t == 0) wn[j] = sqrt(red[0]);
}

__global__ __launch_bounds__(512, 8)
void snn_fused(const float* __restrict__ x, const float* __restrict__ W,
               const float* __restrict__ W32T, const double* __restrict__ wn,
               float* __restrict__ out) {
    // union: 8 x-tile buffers (34848B) / comb f32 [8][64][11] (22528B)
    __shared__ __align__(16) char smem[NBUF * BUF_F * 4];
    __shared__ int qidx[BR * NOUT];            // flagged-element queue (2560B)
    __shared__ int qn;
    float* bufs = reinterpret_cast<float*>(smem);
    float* comb = reinterpret_cast<float*>(smem);

    const int tid = threadIdx.x;
    const int r   = tid & 63;                                  // lane = row
    const int hu  = __builtin_amdgcn_readfirstlane(tid >> 6);  // wave = col octant
    const size_t row0 = (size_t)blockIdx.x * BR;
    const float* xblk = x + row0 * COLS;

    // staging (R9/R10): period P = 4 tiles; 16 lanes cover one row's 256B.
    auto issueP = [&](int P, float4* v) {
        #pragma unroll
        for (int k = 0; k < 2; ++k) {
            int s = tid + 512 * k;
            int row = s >> 4, seg = s & 15;
            int t  = P * TPP + (seg >> 2);
            int tc = (t < NT) ? t : NT - 1;
            v[k] = *reinterpret_cast<const float4*>(
                xblk + (size_t)row * COLS + tc * TW + (seg & 3) * 4);
        }
    };
    auto wldsP = [&](int P, const float4* v) {
        #pragma unroll
        for (int k = 0; k < 2; ++k) {
            int s = tid + 512 * k;
            int row = s >> 4, seg = s & 15;
            int t  = P * TPP + (seg >> 2);
            int tc = (t < NT) ? t : NT - 1;
            float* p = bufs + (tc & (NBUF - 1)) * BUF_F + row * PADW + (seg & 3) * 4;
            p[0] = v[k].x; p[1] = v[k].y; p[2] = v[k].z; p[3] = v[k].w;
        }
    };

    float sacc[NOUT];
    #pragma unroll
    for (int j = 0; j < NOUT; ++j) sacc[j] = 0.0f;
    float nacc = 0.0f;                         // || x_row (this octant) ||^2

    float4 v0[2], v1[2];
    issueP(0, v0); wldsP(0, v0);
    issueP(1, v1);
    __syncthreads();

    for (int p = 0; p < NP; ++p) {
        wldsP(p + 1, v1);
        if (p + 2 <= NP) issueP(p + 2, v0);

        #pragma unroll 1                       // keep W at 20 live f32 (R5 lesson)
        for (int u = 0; u < TPP; ++u) {
            const int tt = p * TPP + u;
            const float* src = bufs + (tt & (NBUF - 1)) * BUF_F + r * PADW + hu * CPH;
            const float* wb  = W32T + (size_t)(tt * TW + hu * CPH) * NOUT;  // s_load
            #pragma unroll
            for (int c = 0; c < CPH; ++c) {
                float xv = src[c];             // ds_read, conflict-free (17)
                nacc = fmaf(xv, xv, nacc);
                #pragma unroll
                for (int j = 0; j < NOUT; ++j)
                    sacc[j] = fmaf(xv, wb[c * NOUT + j], sacc[j]);
            }
        }
        __syncthreads();
        v1[0] = v0[0]; v1[1] = v0[1];
    }

    // tail: tile 48
    {
        const int tt = NT - 1;
        const float* src = bufs + (tt & (NBUF - 1)) * BUF_F + r * PADW + hu * CPH;
        const float* wb  = W32T + (size_t)(tt * TW + hu * CPH) * NOUT;
        #pragma unroll
        for (int c = 0; c < CPH; ++c) {
            float xv = src[c];
            nacc = fmaf(xv, xv, nacc);
            #pragma unroll
            for (int j = 0; j < NOUT; ++j)
                sacc[j] = fmaf(xv, wb[c * NOUT + j], sacc[j]);
        }
    }
    __syncthreads();                           // bufs reads done; comb aliases bufs

    #pragma unroll
    for (int j = 0; j < NOUT; ++j)
        comb[(hu * BR + r) * 11 + j] = sacc[j];
    comb[(hu * BR + r) * 11 + 10] = nacc;
    if (tid == 0) qn = 0;
    __syncthreads();

    for (int i = tid; i < BR * NOUT; i += 512) {   // 640 outputs
        const int rr = i / NOUT, j = i - rr * NOUT;
        double cur = 0.0, nr2 = 0.0;
        #pragma unroll
        for (int o = 0; o < NH; ++o) {
            cur += (double)comb[(o * BR + rr) * 11 + j];
            nr2 += (double)comb[(o * BR + rr) * 11 + 10];
        }
        // worst-case |cur^ - cur_exact| * feedback amplification (sum 0.95^k <= 8.03)
        const double Emem = 9.7e-5 * sqrt(nr2) * wn[j];

        double mem = 0.0, spk = 0.0, s = 0.0, minm = 1e300;
        #pragma unroll
        for (int st = 0; st < STEPS; ++st) {
            mem = 0.95 * mem + cur - spk;      // reset-by-subtraction, thr=1.0
            double d = mem - 1.0;
            minm = fmin(minm, fabs(d));
            spk = (d > 0.0) ? 1.0 : 0.0;
            s  += spk;
        }

        if (minm <= Emem) {                    // decision could flip: queue for f64
            int p = atomicAdd(&qn, 1);
            qidx[p] = i;
        } else {
            out[row0 * NOUT + i] = (float)s;
        }
    }
    __syncthreads();

    // wave-parallel exact f64 recompute of flagged elements (~1-2% of 640)
    const int L  = tid & 63;
    const int nq = qn;
    for (int q = hu; q < nq; q += NH) {        // one wave per flagged element
        const int i  = qidx[q];
        const int rr = i / NOUT, j = i - rr * NOUT;
        const float* xr = x + (row0 + rr) * COLS;
        const float* wr = W + (size_t)j * COLS;
        double a = 0.0;
        for (int c = L; c < COLS; c += 64)     // coalesced 256B bursts
            a = fma((double)xr[c], (double)wr[c], a);
        #pragma unroll
        for (int m = 32; m > 0; m >>= 1)       // f64 butterfly reduce
            a += __shfl_xor(a, m, 64);
        if (L == 0) {
            double mem = 0.0, spk = 0.0, s = 0.0;
            #pragma unroll
            for (int st = 0; st < STEPS; ++st) {
                mem = 0.95 * mem + a - spk;
                spk = (mem > 1.0) ? 1.0 : 0.0;
                s  += spk;
            }
            out[row0 * NOUT + i] = (float)s;
        }
    }
}

extern "C" void kernel_launch(void* const* d_in, const int* in_sizes, int n_in,
                              void* d_out, int out_size, void* d_ws, size_t ws_size,
                              hipStream_t stream) {
    const float* x = (const float*)d_in[0];
    const float* W = (const float*)d_in[1];
    float*  out  = (float*)d_out;
    float*  W32T = (float*)d_ws;
    double* wnrm = (double*)((char*)d_ws + WT_BYTES);

    hipLaunchKernelGGL(w_prep, dim3(NOUT), dim3(256), 0, stream, W, W32T, wnrm);
    hipLaunchKernelGGL(snn_fused, dim3(ROWS / BR), dim3(512), 0, stream,
                       x, W, W32T, wnrm, out);
}